// Round 5
// baseline (399.052 us; speedup 1.0000x reference)
//
#include <hip/hip_runtime.h>
#include <math.h>

// ---------- types ----------
typedef __attribute__((ext_vector_type(8))) __bf16 bf16x8;
typedef __attribute__((ext_vector_type(4))) float  f32x4;
typedef unsigned short ushort_t;
typedef unsigned int   uint_t;

static __device__ inline f32x4 mfma16(bf16x8 a, bf16x8 b, f32x4 c) {
    return __builtin_amdgcn_mfma_f32_16x16x32_bf16(a, b, c, 0, 0, 0);
}

static __device__ inline ushort_t f2b(float f) {
    uint_t u = __builtin_bit_cast(uint_t, f);
    u = (u + 0x7FFFu + ((u >> 16) & 1u)) >> 16;
    return (ushort_t)u;
}
static __device__ inline float b2f(ushort_t u) {
    uint_t x = ((uint_t)u) << 16;
    return __builtin_bit_cast(float, x);
}
static __device__ inline bf16x8 ld8(const ushort_t* p) {
    uint4 v = *(const uint4*)p;
    return __builtin_bit_cast(bf16x8, v);
}
static __device__ inline float fexp2(float x) {
#if __has_builtin(__builtin_amdgcn_exp2f)
    return __builtin_amdgcn_exp2f(x);
#else
    return exp2f(x);
#endif
}

// async global->LDS, 16B per lane; LDS dst = base + lane*16 (wave-uniform base!)
static __device__ inline void gl_lds16(const ushort_t* g, ushort_t* l) {
    __builtin_amdgcn_global_load_lds(
        (const __attribute__((address_space(1))) void*)(g),
        (__attribute__((address_space(3))) void*)(l),
        16, 0, 0);
}

// ---------- fused fp32 -> bf16 convert for x, Wq, Wk, Wv, Wo ----------
__global__ __launch_bounds__(256) void cvt_all(const float* __restrict__ x,
                                               const float* __restrict__ wq,
                                               const float* __restrict__ wk,
                                               const float* __restrict__ wv,
                                               const float* __restrict__ wo,
                                               ushort_t* __restrict__ dst) {
    const size_t i = (size_t)(blockIdx.x * 256 + threadIdx.x) * 4;
    const float* src; size_t off;
    if (i < 4194304)       { src = x;  off = 0; }
    else if (i < 8388608)  { src = wq; off = 4194304; }
    else if (i < 9437184)  { src = wk; off = 8388608; }
    else if (i < 10485760) { src = wv; off = 9437184; }
    else                   { src = wo; off = 10485760; }
    float4 v = *(const float4*)(src + (i - off));
    ushort4 o;
    o.x = f2b(v.x); o.y = f2b(v.y); o.z = f2b(v.z); o.w = f2b(v.w);
    *(ushort4*)(dst + i) = o;
}

// ---------- GEMM-NT: 128x128 tile, BK=64, DOUBLE-BUFFERED async LDS ----------
// C[M,N] = A[M,K]*Bt[N,K]^T. 256 thr = 4 waves 2x2, wave tile 64x64,
// 32 MFMA per barrier. One __syncthreads per 64-K step; the prefetch issued
// right after the barrier has a full 32-MFMA compute phase to land, so the
// vmcnt(0) drain at the next barrier is cheap. K % 128 == 0.
template <int OUTB>
__global__ __launch_bounds__(256) void gemm_db2(const ushort_t* __restrict__ A,
                                                const ushort_t* __restrict__ Bt,
                                                void* __restrict__ Cout,
                                                int M, int N, int K) {
    __shared__ ushort_t As[2 * 8192];   // 2 x 16 KB: [chunk(8)][row(128)][8]
    __shared__ ushort_t Bs[2 * 8192];
    const int tid  = threadIdx.x;
    const int lane = tid & 63, wave = tid >> 6;
    const int wr = wave >> 1, wc = wave & 1;
    const int qn = lane & 15, quad = lane >> 4;
    const long m0 = (long)blockIdx.y * 128, n0 = (long)blockIdx.x * 128;

    const ushort_t* ga = A  + (m0 + lane) * K + wave * 8;
    const ushort_t* gb = Bt + (n0 + lane) * K + wave * 8;
    const long r64 = 64L * K;

#define ISSUE(k0, buf)                                                        \
    do {                                                                      \
        gl_lds16(ga + (k0),            As + (buf) * 8192 + wave * 1024);      \
        gl_lds16(ga + r64 + (k0),      As + (buf) * 8192 + wave * 1024 + 512);\
        gl_lds16(ga + (k0) + 32,       As + (buf) * 8192 + (wave + 4) * 1024);\
        gl_lds16(ga + r64 + (k0) + 32, As + (buf) * 8192 + (wave + 4) * 1024 + 512);\
        gl_lds16(gb + (k0),            Bs + (buf) * 8192 + wave * 1024);      \
        gl_lds16(gb + r64 + (k0),      Bs + (buf) * 8192 + wave * 1024 + 512);\
        gl_lds16(gb + (k0) + 32,       Bs + (buf) * 8192 + (wave + 4) * 1024);\
        gl_lds16(gb + r64 + (k0) + 32, Bs + (buf) * 8192 + (wave + 4) * 1024 + 512);\
    } while (0)

#define COMPUTE(buf)                                                          \
    do {                                                                      \
        _Pragma("unroll")                                                     \
        for (int kk = 0; kk < 2; kk++) {                                      \
            const int cb = (buf) * 8192 + (kk * 4 + quad) * 1024;             \
            bf16x8 af[4], bfr[4];                                             \
            _Pragma("unroll")                                                 \
            for (int i = 0; i < 4; i++)                                       \
                af[i] = *(const bf16x8*)(As + cb + (wr * 64 + i * 16 + qn) * 8);\
            _Pragma("unroll")                                                 \
            for (int j = 0; j < 4; j++)                                       \
                bfr[j] = *(const bf16x8*)(Bs + cb + (wc * 64 + j * 16 + qn) * 8);\
            _Pragma("unroll")                                                 \
            for (int i = 0; i < 4; i++)                                       \
                _Pragma("unroll")                                             \
                for (int j = 0; j < 4; j++)                                   \
                    acc[i][j] = mfma16(af[i], bfr[j], acc[i][j]);             \
        }                                                                     \
    } while (0)

    f32x4 zero = {0.f, 0.f, 0.f, 0.f};
    f32x4 acc[4][4];
    for (int i = 0; i < 4; i++)
        for (int j = 0; j < 4; j++) acc[i][j] = zero;

    ISSUE(0, 0);
    for (int k0 = 0; k0 < K; k0 += 128) {
        __syncthreads();                       // buf0 loads landed
        ISSUE(k0 + 64, 1);                     // prefetch buf1 (full phase in flight)
        COMPUTE(0);
        __syncthreads();                       // buf1 loads landed
        if (k0 + 128 < K) ISSUE(k0 + 128, 0);  // prefetch buf0
        COMPUTE(1);
    }
#undef ISSUE
#undef COMPUTE
    #pragma unroll
    for (int i = 0; i < 4; i++)
        #pragma unroll
        for (int j = 0; j < 4; j++)
            #pragma unroll
            for (int r = 0; r < 4; r++) {
                long row = m0 + wr * 64 + i * 16 + quad * 4 + r;
                long col = n0 + wc * 64 + j * 16 + qn;
                if (OUTB)
                    ((ushort_t*)Cout)[row * N + col] = f2b(acc[i][j][r]);
                else
                    ((float*)Cout)[row * N + col] = acc[i][j][r];
            }
}

// ---------- fused RoPE for q and k (bf16 in/out, strided src) ----------
__global__ __launch_bounds__(256) void rope_both(const ushort_t* __restrict__ qkv,
                                                 const float* __restrict__ cs,
                                                 const float* __restrict__ sn,
                                                 ushort_t* __restrict__ qd,
                                                 ushort_t* __restrict__ kd) {
    const int idx = blockIdx.x * 256 + threadIdx.x;
    if (idx < 4194304) {        // q: [2048, 2048], scale = (1/8)*log2(e)
        const int t = idx >> 11, col = idx & 2047, d = col & 63;
        const ushort_t* row = qkv + (size_t)t * 3072;
        const float v  = b2f(row[col]);
        const float pr = (d < 32) ? -b2f(row[col + 32]) : b2f(row[col - 32]);
        qd[idx] = f2b((v * cs[t * 64 + d] + pr * sn[t * 64 + d]) * 0.18033688f);
    } else {                    // k: [2048, 512]
        const int j = idx - 4194304;
        const int t = j >> 9, col = j & 511, d = col & 63;
        const ushort_t* row = qkv + (size_t)t * 3072 + 2048;
        const float v  = b2f(row[col]);
        const float pr = (d < 32) ? -b2f(row[col + 32]) : b2f(row[col - 32]);
        kd[j] = f2b(v * cs[t * 64 + d] + pr * sn[t * 64 + d]);
    }
}

// ---------- V transpose: qkv V columns -> Vt_g[512][2048] (row = kvh*64+d) ----------
__global__ __launch_bounds__(256) void vtrans(const ushort_t* __restrict__ qkv,
                                              ushort_t* __restrict__ vt) {
    __shared__ ushort_t t[64][65];
    const int tb = blockIdx.x * 64;          // s block (32 blocks)
    const int db = blockIdx.y * 64;          // d block (8 blocks)
    const int r  = threadIdx.x >> 3;         // 0..31
    const int c8 = (threadIdx.x & 7) * 8;    // 0,8,..56
    #pragma unroll
    for (int rr = 0; rr < 2; rr++) {
        const int row = r + rr * 32;
        uint4 v = *(const uint4*)(qkv + (size_t)(tb + row) * 3072 + 2560 + db + c8);
        *(uint4*)&t[row][c8] = *(uint4*)&v;
    }
    __syncthreads();
    #pragma unroll
    for (int rr = 0; rr < 2; rr++) {
        const int d = r + rr * 32;
        ushort4 o0, o1;
        o0.x = t[c8 + 0][d]; o0.y = t[c8 + 1][d]; o0.z = t[c8 + 2][d]; o0.w = t[c8 + 3][d];
        o1.x = t[c8 + 4][d]; o1.y = t[c8 + 5][d]; o1.z = t[c8 + 6][d]; o1.w = t[c8 + 7][d];
        *(ushort4*)(vt + (size_t)(db + d) * 2048 + tb + c8)     = o0;
        *(ushort4*)(vt + (size_t)(db + d) * 2048 + tb + c8 + 4) = o1;
    }
}

// ---------- flash attention, causal, GQA G=4, barrier-free ----------
// Q pre-scaled by (1/8)*log2(e); p = 2^score (fixed-reference softmax).
// Block = head x 2 paired q-blocks (rb, 31-rb); 4 waves x 16 q-rows; NO
// __syncthreads: K fragments read directly from global (natural layout),
// V fragments from pre-transposed Vt_g[kvh*64+d][T]. P round-trips through
// per-wave private LDS (in-order DS pipe, no barrier needed).
__global__ __launch_bounds__(256) void attn_kernel(const ushort_t* __restrict__ Q,
                                                   const ushort_t* __restrict__ Kb,
                                                   const ushort_t* __restrict__ Vt,
                                                   ushort_t* __restrict__ Ob) {
    __shared__ ushort_t pl[4][16 * 88];
    const int tid  = threadIdx.x;
    const int lane = tid & 63, wid = tid >> 6;
    const int qn = lane & 15, quad = lane >> 4;
    const int h   = blockIdx.x & 31;
    const int prr = blockIdx.x >> 5;            // 0..15
    const int kvb = (h >> 2) * 64;
    ushort_t* plw = pl[wid];
    f32x4 zero = {0.f, 0.f, 0.f, 0.f};

    for (int half = 0; half < 2; ++half) {
        const int rb = half ? prr : (31 - prr);
        const int q0 = rb << 6;
        const int trow = q0 + wid * 16;
        const ushort_t* qp = Q + (size_t)(trow + qn) * 2048 + h * 64 + quad * 8;
        const bf16x8 qa0 = ld8(qp);
        const bf16x8 qa1 = ld8(qp + 32);

        f32x4 o[4] = {zero, zero, zero, zero};
        float lr[4] = {0.f, 0.f, 0.f, 0.f};

        for (int st = 0; st <= rb; ++st) {
            const int s0 = st << 6;
            // ---- Q K^T : 16 q-rows x 64 s-cols, K frags direct from global
            f32x4 sc[4];
            #pragma unroll
            for (int cb = 0; cb < 4; cb++) {
                const ushort_t* kp = Kb + (size_t)(s0 + cb * 16 + qn) * 512 + kvb + quad * 8;
                f32x4 s = zero;
                s = mfma16(qa0, ld8(kp), s);
                s = mfma16(qa1, ld8(kp + 32), s);
                sc[cb] = s;
            }

            const bool needmask = (st == rb);
            #pragma unroll
            for (int i = 0; i < 4; i++) {
                const int t = trow + quad * 4 + i;
                float v0 = sc[0][i], v1 = sc[1][i], v2 = sc[2][i], v3 = sc[3][i];
                if (needmask) {
                    if (s0 + qn > t)      v0 = -INFINITY;
                    if (s0 + 16 + qn > t) v1 = -INFINITY;
                    if (s0 + 32 + qn > t) v2 = -INFINITY;
                    if (s0 + 48 + qn > t) v3 = -INFINITY;
                }
                const float p0 = fexp2(v0);
                const float p1 = fexp2(v1);
                const float p2 = fexp2(v2);
                const float p3 = fexp2(v3);
                lr[i] += (p0 + p1) + (p2 + p3);
                const int pr = (quad * 4 + i) * 88;
                plw[pr + qn]      = f2b(p0);
                plw[pr + 16 + qn] = f2b(p1);
                plw[pr + 32 + qn] = f2b(p2);
                plw[pr + 48 + qn] = f2b(p3);
            }
            // ---- P V : V frags direct from transposed global
            const bf16x8 pf0 = *(const bf16x8*)(plw + qn * 88 + quad * 8);
            const bf16x8 pf1 = *(const bf16x8*)(plw + qn * 88 + 32 + quad * 8);
            #pragma unroll
            for (int dcb = 0; dcb < 4; dcb++) {
                const ushort_t* vp = Vt + (size_t)(kvb + dcb * 16 + qn) * 2048 + s0 + quad * 8;
                o[dcb] = mfma16(pf0, ld8(vp), o[dcb]);
                o[dcb] = mfma16(pf1, ld8(vp + 32), o[dcb]);
            }
        }
        #pragma unroll
        for (int i = 0; i < 4; i++) {
            float s = lr[i];
            #pragma unroll
            for (int off = 1; off < 16; off <<= 1)
                s += __shfl_xor(s, off, 64);
            const float inv = 1.0f / s;
            ushort_t* ob = Ob + (size_t)(trow + quad * 4 + i) * 2048 + h * 64 + qn;
            ob[0]  = f2b(o[0][i] * inv);
            ob[16] = f2b(o[1][i] * inv);
            ob[32] = f2b(o[2][i] * inv);
            ob[48] = f2b(o[3][i] * inv);
        }
    }
}

// ---------- launch ----------
extern "C" void kernel_launch(void* const* d_in, const int* in_sizes, int n_in,
                              void* d_out, int out_size, void* d_ws, size_t ws_size,
                              hipStream_t stream) {
    const float* x    = (const float*)d_in[0];
    const float* cosp = (const float*)d_in[1];
    const float* sinp = (const float*)d_in[2];
    // d_in[3] = attention_mask_4d (pure causal; recomputed in-kernel)
    const float* Wq = (const float*)d_in[4];
    const float* Wk = (const float*)d_in[5];
    const float* Wv = (const float*)d_in[6];
    const float* Wo = (const float*)d_in[7];

    char* ws = (char*)d_ws;
    ushort_t* xb    = (ushort_t*)(ws + 0);          //  8 MiB x bf16            [2048,2048]
    ushort_t* wqkvb = (ushort_t*)(ws + 8388608);    // 12 MiB [Wq;Wk;Wv] bf16   [3072,2048]
    ushort_t* wob   = (ushort_t*)(ws + 20971520);   //  8 MiB Wo bf16           [2048,2048]
    ushort_t* qkvb  = (ushort_t*)(ws + 29360128);   // 12 MiB qkv bf16          [2048,3072]
    ushort_t* qbb   = (ushort_t*)(ws + 41943040);   //  8 MiB q roped bf16      [2048,2048]
    ushort_t* kbb   = (ushort_t*)(ws + 50331648);   //  2 MiB k roped bf16      [2048,512]
    ushort_t* ab    = (ushort_t*)(ws + 52428800);   //  8 MiB attn out bf16     [2048,2048]
    ushort_t* vtg   = (ushort_t*)(ws + 60817408);   //  2 MiB V^T bf16          [512,2048]
    (void)ws_size; (void)in_sizes; (void)n_in; (void)out_size;

    cvt_all<<<14336, 256, 0, stream>>>(x, Wq, Wk, Wv, Wo, xb);

    // fused QKV projection: [2048,3072] = x @ [Wq;Wk;Wv]^T ; 24x16 = 384 blocks
    gemm_db2<1><<<dim3(24, 16), 256, 0, stream>>>(xb, wqkvb, qkvb, 2048, 3072, 2048);

    // fused RoPE (q scale carries softmax*log2e) + V transpose
    rope_both<<<20480, 256, 0, stream>>>(qkvb, cosp, sinp, qbb, kbb);
    vtrans<<<dim3(32, 8), 256, 0, stream>>>(qkvb, vtg);

    attn_kernel<<<512, 256, 0, stream>>>(qbb, kbb, vtg, ab);

    // O-projection: 16x16 = 256 blocks
    gemm_db2<0><<<dim3(16, 16), 256, 0, stream>>>(ab, wob, (float*)d_out, 2048, 2048, 2048);
}

// Round 6
// 314.405 us; speedup vs baseline: 1.2692x; 1.2692x over previous
//
#include <hip/hip_runtime.h>
#include <math.h>

// ---------- types ----------
typedef __attribute__((ext_vector_type(8))) __bf16 bf16x8;
typedef __attribute__((ext_vector_type(4))) float  f32x4;
typedef unsigned short ushort_t;
typedef unsigned int   uint_t;

static __device__ inline f32x4 mfma16(bf16x8 a, bf16x8 b, f32x4 c) {
    return __builtin_amdgcn_mfma_f32_16x16x32_bf16(a, b, c, 0, 0, 0);
}

static __device__ inline ushort_t f2b(float f) {
    uint_t u = __builtin_bit_cast(uint_t, f);
    u = (u + 0x7FFFu + ((u >> 16) & 1u)) >> 16;
    return (ushort_t)u;
}
static __device__ inline float b2f(ushort_t u) {
    uint_t x = ((uint_t)u) << 16;
    return __builtin_bit_cast(float, x);
}
static __device__ inline bf16x8 ld8(const ushort_t* p) {
    uint4 v = *(const uint4*)p;
    return __builtin_bit_cast(bf16x8, v);
}
static __device__ inline float fexp2(float x) {
#if __has_builtin(__builtin_amdgcn_exp2f)
    return __builtin_amdgcn_exp2f(x);
#else
    return exp2f(x);
#endif
}

// async global->LDS, 16B per lane; LDS dst = base + lane*16 (wave-uniform base!)
static __device__ inline void gl_lds16(const ushort_t* g, ushort_t* l) {
    __builtin_amdgcn_global_load_lds(
        (const __attribute__((address_space(1))) void*)(g),
        (__attribute__((address_space(3))) void*)(l),
        16, 0, 0);
}

// ---------- fused fp32 -> bf16 convert for x, Wq, Wk, Wv, Wo ----------
__global__ __launch_bounds__(256) void cvt_all(const float* __restrict__ x,
                                               const float* __restrict__ wq,
                                               const float* __restrict__ wk,
                                               const float* __restrict__ wv,
                                               const float* __restrict__ wo,
                                               ushort_t* __restrict__ dst) {
    const size_t i = (size_t)(blockIdx.x * 256 + threadIdx.x) * 4;
    const float* src; size_t off;
    if (i < 4194304)       { src = x;  off = 0; }
    else if (i < 8388608)  { src = wq; off = 4194304; }
    else if (i < 9437184)  { src = wk; off = 8388608; }
    else if (i < 10485760) { src = wv; off = 9437184; }
    else                   { src = wo; off = 10485760; }
    float4 v = *(const float4*)(src + (i - off));
    ushort4 o;
    o.x = f2b(v.x); o.y = f2b(v.y); o.z = f2b(v.z); o.w = f2b(v.w);
    *(ushort4*)(dst + i) = o;
}

// ---------- GEMM-NT, m97-style: 128x128 tile, BK=64, async LDS staging ----------
// (R3-proven version: 73 us at 2048-class sizes.)
template <int OUTB>
__global__ __launch_bounds__(256) void gemm_async(const ushort_t* __restrict__ A,
                                                  const ushort_t* __restrict__ Bt,
                                                  void* __restrict__ Cout,
                                                  int M, int N, int K) {
    __shared__ ushort_t As[8 * 128 * 8];   // 16 KB
    __shared__ ushort_t Bs[8 * 128 * 8];   // 16 KB
    const int tid  = threadIdx.x;
    const int lane = tid & 63, wave = tid >> 6;
    const int wr = wave >> 1, wc = wave & 1;
    const int qn = lane & 15, quad = lane >> 4;
    const long m0 = (long)blockIdx.y * 128, n0 = (long)blockIdx.x * 128;

    const ushort_t* ga = A  + (m0 + lane) * K + wave * 8;
    const ushort_t* gb = Bt + (n0 + lane) * K + wave * 8;
    ushort_t* laL = As + wave * 1024;
    ushort_t* laH = As + (wave + 4) * 1024;
    ushort_t* lbL = Bs + wave * 1024;
    ushort_t* lbH = Bs + (wave + 4) * 1024;

    f32x4 zero = {0.f, 0.f, 0.f, 0.f};
    f32x4 acc[4][4];
    for (int i = 0; i < 4; i++)
        for (int j = 0; j < 4; j++) acc[i][j] = zero;

    const long r64 = 64L * K;
    for (int k0 = 0; k0 < K; k0 += 64) {
        __syncthreads();
        gl_lds16(ga + k0,            laL);
        gl_lds16(ga + r64 + k0,      laL + 512);
        gl_lds16(ga + k0 + 32,       laH);
        gl_lds16(ga + r64 + k0 + 32, laH + 512);
        gl_lds16(gb + k0,            lbL);
        gl_lds16(gb + r64 + k0,      lbL + 512);
        gl_lds16(gb + k0 + 32,       lbH);
        gl_lds16(gb + r64 + k0 + 32, lbH + 512);
        __syncthreads();
        #pragma unroll
        for (int kk = 0; kk < 2; kk++) {
            bf16x8 af[4], bfr[4];
            const int cb = (kk * 4 + quad) * 1024;
            #pragma unroll
            for (int i = 0; i < 4; i++)
                af[i] = *(const bf16x8*)(As + cb + (wr * 64 + i * 16 + qn) * 8);
            #pragma unroll
            for (int j = 0; j < 4; j++)
                bfr[j] = *(const bf16x8*)(Bs + cb + (wc * 64 + j * 16 + qn) * 8);
            #pragma unroll
            for (int i = 0; i < 4; i++)
                #pragma unroll
                for (int j = 0; j < 4; j++)
                    acc[i][j] = mfma16(af[i], bfr[j], acc[i][j]);
        }
    }
    #pragma unroll
    for (int i = 0; i < 4; i++)
        #pragma unroll
        for (int j = 0; j < 4; j++)
            #pragma unroll
            for (int r = 0; r < 4; r++) {
                long row = m0 + wr * 64 + i * 16 + quad * 4 + r;
                long col = n0 + wc * 64 + j * 16 + qn;
                if (OUTB)
                    ((ushort_t*)Cout)[row * N + col] = f2b(acc[i][j][r]);
                else
                    ((float*)Cout)[row * N + col] = acc[i][j][r];
            }
}

// ---------- fused RoPE for q and k (bf16 in/out, strided src) ----------
__global__ __launch_bounds__(256) void rope_both(const ushort_t* __restrict__ qkv,
                                                 const float* __restrict__ cs,
                                                 const float* __restrict__ sn,
                                                 ushort_t* __restrict__ qd,
                                                 ushort_t* __restrict__ kd) {
    const int idx = blockIdx.x * 256 + threadIdx.x;
    if (idx < 4194304) {        // q: [2048, 2048], scale = (1/8)*log2(e)
        const int t = idx >> 11, col = idx & 2047, d = col & 63;
        const ushort_t* row = qkv + (size_t)t * 3072;
        const float v  = b2f(row[col]);
        const float pr = (d < 32) ? -b2f(row[col + 32]) : b2f(row[col - 32]);
        qd[idx] = f2b((v * cs[t * 64 + d] + pr * sn[t * 64 + d]) * 0.18033688f);
    } else {                    // k: [2048, 512]
        const int j = idx - 4194304;
        const int t = j >> 9, col = j & 511, d = col & 63;
        const ushort_t* row = qkv + (size_t)t * 3072 + 2048;
        const float v  = b2f(row[col]);
        const float pr = (d < 32) ? -b2f(row[col + 32]) : b2f(row[col - 32]);
        kd[j] = f2b(v * cs[t * 64 + d] + pr * sn[t * 64 + d]);
    }
}

// ---------- V transpose: qkv V columns -> Vt_g[512][2048] (row = kvh*64+d) ----------
__global__ __launch_bounds__(256) void vtrans(const ushort_t* __restrict__ qkv,
                                              ushort_t* __restrict__ vt) {
    __shared__ ushort_t t[64][65];
    const int tb = blockIdx.x * 64;          // s block (32 blocks)
    const int db = blockIdx.y * 64;          // d block (8 blocks)
    const int r  = threadIdx.x >> 3;         // 0..31
    const int c8 = (threadIdx.x & 7) * 8;    // 0,8,..56
    #pragma unroll
    for (int rr = 0; rr < 2; rr++) {
        const int row = r + rr * 32;
        uint4 v = *(const uint4*)(qkv + (size_t)(tb + row) * 3072 + 2560 + db + c8);
        *(uint4*)&t[row][c8] = *(uint4*)&v;
    }
    __syncthreads();
    #pragma unroll
    for (int rr = 0; rr < 2; rr++) {
        const int d = r + rr * 32;
        ushort4 o0, o1;
        o0.x = t[c8 + 0][d]; o0.y = t[c8 + 1][d]; o0.z = t[c8 + 2][d]; o0.w = t[c8 + 3][d];
        o1.x = t[c8 + 4][d]; o1.y = t[c8 + 5][d]; o1.z = t[c8 + 6][d]; o1.w = t[c8 + 7][d];
        *(ushort4*)(vt + (size_t)(db + d) * 2048 + tb + c8)     = o0;
        *(ushort4*)(vt + (size_t)(db + d) * 2048 + tb + c8 + 4) = o1;
    }
}

// ---------- flash attention, causal, GQA G=4 ----------
// Fixed-reference softmax (Q pre-scaled by (1/8)*log2(e); p = 2^score).
// Block = one head x 128 q-rows; 4 waves x 32 q-rows (2 row-groups of 16).
// K tile AND pre-transposed V tile staged via global_load_lds into chunk-major
// LDS [chunk(8)][row(64)][8] (conflict-free b128 frag reads, no scalar staging
// writes). Double-buffered, ONE barrier per tile (tiles/block = 2*qb+2, even).
// P round-trips per-wave LDS (stride 72). Heavy q-blocks launched first.
__global__ __launch_bounds__(256) void attn_kernel(const ushort_t* __restrict__ Q,
                                                   const ushort_t* __restrict__ Kb,
                                                   const ushort_t* __restrict__ Vt,
                                                   ushort_t* __restrict__ Ob) {
    __shared__ ushort_t Ks[2 * 4096];     // 16 KB: [buf][chunk d/8][s-row 64][8]
    __shared__ ushort_t Vs[2 * 4096];     // 16 KB: [buf][chunk s/8][d-row 64][8]
    __shared__ ushort_t pl[4 * 32 * 72];  // 18 KB: per-wave P, 32 rows x 64 (stride 72)
    const int tid  = threadIdx.x;
    const int lane = tid & 63, wid = tid >> 6;
    const int qn = lane & 15, quad = lane >> 4;
    const int h   = blockIdx.x & 31;
    const int qb  = 15 - (blockIdx.x >> 5);     // heavy first
    const int kvb = (h >> 2) * 64;
    const int trow = qb * 128 + wid * 32;
    ushort_t* plw = pl + wid * 32 * 72;
    f32x4 zero = {0.f, 0.f, 0.f, 0.f};

    // Q fragments: group A rows trow..+15, group B rows trow+16..+31
    const ushort_t* qpA = Q + (size_t)(trow + qn) * 2048 + h * 64 + quad * 8;
    const bf16x8 qA0 = ld8(qpA), qA1 = ld8(qpA + 32);
    const ushort_t* qpB = qpA + 16 * 2048;
    const bf16x8 qB0 = ld8(qpB), qB1 = ld8(qpB + 32);

    f32x4 oA[4] = {zero, zero, zero, zero};
    f32x4 oB[4] = {zero, zero, zero, zero};
    float lA[4] = {0.f, 0.f, 0.f, 0.f};
    float lB[4] = {0.f, 0.f, 0.f, 0.f};
    const int ntiles = qb * 2 + 2;

#define STAGE(s0, buf)                                                         \
    do {                                                                       \
        const ushort_t* kg = Kb + (size_t)((s0) + lane) * 512 + kvb + wid * 8; \
        gl_lds16(kg,      Ks + (buf) * 4096 + wid * 512);                      \
        gl_lds16(kg + 32, Ks + (buf) * 4096 + (wid + 4) * 512);                \
        const ushort_t* vg = Vt + (size_t)(kvb + lane) * 2048 + (s0) + wid * 8;\
        gl_lds16(vg,      Vs + (buf) * 4096 + wid * 512);                      \
        gl_lds16(vg + 32, Vs + (buf) * 4096 + (wid + 4) * 512);                \
    } while (0)

#define COMPUTE(s0, buf)                                                       \
    do {                                                                       \
        f32x4 scA[4], scB[4];                                                  \
        _Pragma("unroll")                                                      \
        for (int cb = 0; cb < 4; cb++) {                                       \
            const bf16x8 kf0 = *(const bf16x8*)(Ks + (buf) * 4096 + quad * 512 + (cb * 16 + qn) * 8);       \
            const bf16x8 kf1 = *(const bf16x8*)(Ks + (buf) * 4096 + (quad + 4) * 512 + (cb * 16 + qn) * 8); \
            f32x4 s = mfma16(qA0, kf0, zero); scA[cb] = mfma16(qA1, kf1, s);   \
            f32x4 t = mfma16(qB0, kf0, zero); scB[cb] = mfma16(qB1, kf1, t);   \
        }                                                                      \
        const bool needmask = ((s0) + 63 > trow);                              \
        _Pragma("unroll")                                                      \
        for (int i = 0; i < 4; i++) {                                          \
            const int tA = trow + quad * 4 + i, tB = tA + 16;                  \
            _Pragma("unroll")                                                  \
            for (int cb = 0; cb < 4; cb++) {                                   \
                const int col = (s0) + cb * 16 + qn;                           \
                float vA = scA[cb][i], vB = scB[cb][i];                        \
                if (needmask) {                                                \
                    if (col > tA) vA = -INFINITY;                              \
                    if (col > tB) vB = -INFINITY;                              \
                }                                                              \
                const float pA = fexp2(vA), pB = fexp2(vB);                    \
                lA[i] += pA; lB[i] += pB;                                      \
                plw[(quad * 4 + i) * 72 + cb * 16 + qn]      = f2b(pA);        \
                plw[(16 + quad * 4 + i) * 72 + cb * 16 + qn] = f2b(pB);        \
            }                                                                  \
        }                                                                      \
        const bf16x8 pfA0 = *(const bf16x8*)(plw + qn * 72 + quad * 8);        \
        const bf16x8 pfA1 = *(const bf16x8*)(plw + qn * 72 + 32 + quad * 8);   \
        const bf16x8 pfB0 = *(const bf16x8*)(plw + (16 + qn) * 72 + quad * 8); \
        const bf16x8 pfB1 = *(const bf16x8*)(plw + (16 + qn) * 72 + 32 + quad * 8); \
        _Pragma("unroll")                                                      \
        for (int dcb = 0; dcb < 4; dcb++) {                                    \
            const bf16x8 vf0 = *(const bf16x8*)(Vs + (buf) * 4096 + quad * 512 + (dcb * 16 + qn) * 8);       \
            const bf16x8 vf1 = *(const bf16x8*)(Vs + (buf) * 4096 + (quad + 4) * 512 + (dcb * 16 + qn) * 8); \
            oA[dcb] = mfma16(pfA0, vf0, oA[dcb]);                              \
            oA[dcb] = mfma16(pfA1, vf1, oA[dcb]);                              \
            oB[dcb] = mfma16(pfB0, vf0, oB[dcb]);                              \
            oB[dcb] = mfma16(pfB1, vf1, oB[dcb]);                              \
        }                                                                      \
    } while (0)

    STAGE(0, 0);
    for (int t = 0; t < ntiles; t += 2) {
        __syncthreads();                       // buf0 DMA landed; buf1 free
        STAGE((t + 1) * 64, 1);                // prefetch buf1
        COMPUTE(t * 64, 0);
        __syncthreads();                       // buf1 landed; all done reading buf0
        if (t + 2 < ntiles) STAGE((t + 2) * 64, 0);
        COMPUTE((t + 1) * 64, 1);
    }
#undef STAGE
#undef COMPUTE

    #pragma unroll
    for (int i = 0; i < 4; i++) {
        float sA = lA[i], sB = lB[i];
        #pragma unroll
        for (int off = 1; off < 16; off <<= 1) {
            sA += __shfl_xor(sA, off, 64);
            sB += __shfl_xor(sB, off, 64);
        }
        const float invA = 1.0f / sA, invB = 1.0f / sB;
        ushort_t* obA = Ob + (size_t)(trow + quad * 4 + i) * 2048 + h * 64 + qn;
        ushort_t* obB = obA + 16 * 2048;
        obA[0]  = f2b(oA[0][i] * invA);
        obA[16] = f2b(oA[1][i] * invA);
        obA[32] = f2b(oA[2][i] * invA);
        obA[48] = f2b(oA[3][i] * invA);
        obB[0]  = f2b(oB[0][i] * invB);
        obB[16] = f2b(oB[1][i] * invB);
        obB[32] = f2b(oB[2][i] * invB);
        obB[48] = f2b(oB[3][i] * invB);
    }
}

// ---------- launch ----------
extern "C" void kernel_launch(void* const* d_in, const int* in_sizes, int n_in,
                              void* d_out, int out_size, void* d_ws, size_t ws_size,
                              hipStream_t stream) {
    const float* x    = (const float*)d_in[0];
    const float* cosp = (const float*)d_in[1];
    const float* sinp = (const float*)d_in[2];
    // d_in[3] = attention_mask_4d (pure causal; recomputed in-kernel)
    const float* Wq = (const float*)d_in[4];
    const float* Wk = (const float*)d_in[5];
    const float* Wv = (const float*)d_in[6];
    const float* Wo = (const float*)d_in[7];

    char* ws = (char*)d_ws;
    ushort_t* xb    = (ushort_t*)(ws + 0);          //  8 MiB x bf16            [2048,2048]
    ushort_t* wqkvb = (ushort_t*)(ws + 8388608);    // 12 MiB [Wq;Wk;Wv] bf16   [3072,2048]
    ushort_t* wob   = (ushort_t*)(ws + 20971520);   //  8 MiB Wo bf16           [2048,2048]
    ushort_t* qkvb  = (ushort_t*)(ws + 29360128);   // 12 MiB qkv bf16          [2048,3072]
    ushort_t* qbb   = (ushort_t*)(ws + 41943040);   //  8 MiB q roped bf16      [2048,2048]
    ushort_t* kbb   = (ushort_t*)(ws + 50331648);   //  2 MiB k roped bf16      [2048,512]
    ushort_t* ab    = (ushort_t*)(ws + 52428800);   //  8 MiB attn out bf16     [2048,2048]
    ushort_t* vtg   = (ushort_t*)(ws + 60817408);   //  2 MiB V^T bf16          [512,2048]
    (void)ws_size; (void)in_sizes; (void)n_in; (void)out_size;

    cvt_all<<<14336, 256, 0, stream>>>(x, Wq, Wk, Wv, Wo, xb);

    // fused QKV projection: [2048,3072] = x @ [Wq;Wk;Wv]^T ; 24x16 = 384 blocks
    gemm_async<1><<<dim3(24, 16), 256, 0, stream>>>(xb, wqkvb, qkvb, 2048, 3072, 2048);

    // fused RoPE (q scale carries softmax*log2e) + V transpose
    rope_both<<<20480, 256, 0, stream>>>(qkvb, cosp, sinp, qbb, kbb);
    vtrans<<<dim3(32, 8), 256, 0, stream>>>(qkvb, vtg);

    attn_kernel<<<512, 256, 0, stream>>>(qbb, kbb, vtg, ab);

    // O-projection: 16x16 = 256 blocks
    gemm_async<0><<<dim3(16, 16), 256, 0, stream>>>(ab, wob, (float*)d_out, 2048, 2048, 2048);
}

// Round 8
// 287.567 us; speedup vs baseline: 1.3877x; 1.0933x over previous
//
#include <hip/hip_runtime.h>
#include <math.h>

// ---------- types ----------
typedef __attribute__((ext_vector_type(8))) __bf16 bf16x8;
typedef __attribute__((ext_vector_type(4))) float  f32x4;
typedef unsigned short ushort_t;
typedef unsigned int   uint_t;

static __device__ inline f32x4 mfma16(bf16x8 a, bf16x8 b, f32x4 c) {
    return __builtin_amdgcn_mfma_f32_16x16x32_bf16(a, b, c, 0, 0, 0);
}

static __device__ inline ushort_t f2b(float f) {
    uint_t u = __builtin_bit_cast(uint_t, f);
    u = (u + 0x7FFFu + ((u >> 16) & 1u)) >> 16;
    return (ushort_t)u;
}
static __device__ inline float b2f(ushort_t u) {
    uint_t x = ((uint_t)u) << 16;
    return __builtin_bit_cast(float, x);
}
static __device__ inline bf16x8 ld8(const ushort_t* p) {
    uint4 v = *(const uint4*)p;
    return __builtin_bit_cast(bf16x8, v);
}
static __device__ inline float fexp2(float x) {
#if __has_builtin(__builtin_amdgcn_exp2f)
    return __builtin_amdgcn_exp2f(x);
#else
    return exp2f(x);
#endif
}

// async global->LDS, 16B per lane; LDS dst = base + lane*16 (wave-uniform base!)
static __device__ inline void gl_lds16(const ushort_t* g, ushort_t* l) {
    __builtin_amdgcn_global_load_lds(
        (const __attribute__((address_space(1))) void*)(g),
        (__attribute__((address_space(3))) void*)(l),
        16, 0, 0);
}

// ---------- ws layout (peak = 62,914,560 B, same as R6) ----------
#define WS_XB     0          //  8 MiB x bf16           [2048,2048]   (dead after QKV gemm)
#define WS_WQKV   8388608    // 12 MiB [Wq;Wk;Wv] bf16  [3072,2048]   (dead after QKV gemm)
#define WS_WO     20971520   //  8 MiB Wo bf16          [2048,2048]
#define WS_P0     29360128   // 12 MiB QKV partial 0 bf16 [2048,3072] (dead after fuse)
#define WS_P1     41943040   // 12 MiB QKV partial 1 bf16 [2048,3072] (dead after fuse)
#define WS_QBB    0          //  8 MiB q roped bf16     (overlays xb)
#define WS_KBB    8388608    //  2 MiB k roped bf16     (overlays wqkvb head)
#define WS_VTG    10485760   //  2 MiB V^T bf16 [512,2048]
#define WS_AB     12582912   //  8 MiB attn out bf16    (ends exactly at WS_WO)
#define WS_O0     29360128   // 16 MiB O partial 0 fp32 (overlays p0)
#define WS_O1     46137344   // 16 MiB O partial 1 fp32 (ends 62914560)

// ---------- fp32 -> bf16 convert for x|Wq|Wk|Wv|Wo (contiguous dst) ----------
__global__ __launch_bounds__(256) void cvt_all(const float* __restrict__ x,
                                               const float* __restrict__ wq,
                                               const float* __restrict__ wk,
                                               const float* __restrict__ wv,
                                               const float* __restrict__ wo,
                                               ushort_t* __restrict__ dst) {
    const size_t i = (size_t)(blockIdx.x * 256 + threadIdx.x) * 4;
    const float* src; size_t off;
    if (i < 4194304)       { src = x;  off = 0; }
    else if (i < 8388608)  { src = wq; off = 4194304; }
    else if (i < 9437184)  { src = wk; off = 8388608; }
    else if (i < 10485760) { src = wv; off = 9437184; }
    else                   { src = wo; off = 10485760; }
    float4 v = *(const float4*)(src + (i - off));
    ushort4 o;
    o.x = f2b(v.x); o.y = f2b(v.y); o.z = f2b(v.z); o.w = f2b(v.w);
    *(ushort4*)(dst + i) = o;
}

// ---------- GEMM-NT tile body, m97-style (proven R3/R6) ----------
// 128x128, BK=64, async LDS staging, K-range [kbeg,kend). As/Bs: 8192 ushorts.
template <int OUTB>
static __device__ void gemm_tile(const ushort_t* __restrict__ A,
                                 const ushort_t* __restrict__ Bt,
                                 void* __restrict__ Cout,
                                 int N, int K, long m0, long n0,
                                 int kbeg, int kend,
                                 ushort_t* As, ushort_t* Bs) {
    const int tid  = threadIdx.x;
    const int lane = tid & 63, wave = tid >> 6;
    const int wr = wave >> 1, wc = wave & 1;
    const int qn = lane & 15, quad = lane >> 4;

    const ushort_t* ga = A  + (m0 + lane) * K + wave * 8;
    const ushort_t* gb = Bt + (n0 + lane) * K + wave * 8;
    ushort_t* laL = As + wave * 1024;
    ushort_t* laH = As + (wave + 4) * 1024;
    ushort_t* lbL = Bs + wave * 1024;
    ushort_t* lbH = Bs + (wave + 4) * 1024;

    f32x4 zero = {0.f, 0.f, 0.f, 0.f};
    f32x4 acc[4][4];
    for (int i = 0; i < 4; i++)
        for (int j = 0; j < 4; j++) acc[i][j] = zero;

    const long r64 = 64L * K;
    for (int k0 = kbeg; k0 < kend; k0 += 64) {
        __syncthreads();
        gl_lds16(ga + k0,            laL);
        gl_lds16(ga + r64 + k0,      laL + 512);
        gl_lds16(ga + k0 + 32,       laH);
        gl_lds16(ga + r64 + k0 + 32, laH + 512);
        gl_lds16(gb + k0,            lbL);
        gl_lds16(gb + r64 + k0,      lbL + 512);
        gl_lds16(gb + k0 + 32,       lbH);
        gl_lds16(gb + r64 + k0 + 32, lbH + 512);
        __syncthreads();
        #pragma unroll
        for (int kk = 0; kk < 2; kk++) {
            bf16x8 af[4], bfr[4];
            const int cb = (kk * 4 + quad) * 1024;
            #pragma unroll
            for (int i = 0; i < 4; i++)
                af[i] = *(const bf16x8*)(As + cb + (wr * 64 + i * 16 + qn) * 8);
            #pragma unroll
            for (int j = 0; j < 4; j++)
                bfr[j] = *(const bf16x8*)(Bs + cb + (wc * 64 + j * 16 + qn) * 8);
            #pragma unroll
            for (int i = 0; i < 4; i++)
                #pragma unroll
                for (int j = 0; j < 4; j++)
                    acc[i][j] = mfma16(af[i], bfr[j], acc[i][j]);
        }
    }
    #pragma unroll
    for (int i = 0; i < 4; i++)
        #pragma unroll
        for (int j = 0; j < 4; j++)
            #pragma unroll
            for (int r = 0; r < 4; r++) {
                long row = m0 + wr * 64 + i * 16 + quad * 4 + r;
                long col = n0 + wc * 64 + j * 16 + qn;
                if (OUTB)
                    ((ushort_t*)Cout)[row * N + col] = f2b(acc[i][j][r]);
                else
                    ((float*)Cout)[row * N + col] = acc[i][j][r];
            }
}

// ---------- split-K=2 GEMM wrapper: blockIdx.z picks K-half and dest slab ----------
template <int OUTB>
__global__ __launch_bounds__(256) void gemm_split(const ushort_t* __restrict__ A,
                                                  const ushort_t* __restrict__ Bt,
                                                  void* __restrict__ C0,
                                                  void* __restrict__ C1,
                                                  int N, int K) {
    __shared__ ushort_t As[8192];
    __shared__ ushort_t Bs[8192];
    const int half = blockIdx.z;
    const int kh = K >> 1;
    gemm_tile<OUTB>(A, Bt, half ? C1 : C0, N, K,
                    (long)blockIdx.y * 128, (long)blockIdx.x * 128,
                    half * kh, half * kh + kh, As, Bs);
}

// ---------- fused combine + RoPE + V-transpose ----------
// Reads bf16 partial slabs p0,p1 [2048,3072]; q cols 0..2047 -> rope*scale -> qd,
// k cols 2048..2559 -> rope -> kd, v cols 2560..3071 -> transpose -> vt[512][2048].
// Grid: (48 col-tiles, 32 row-tiles), 256 thr; each block = 64 rows x 64 cols.
__global__ __launch_bounds__(256) void fuse_crv(const ushort_t* __restrict__ p0,
                                                const ushort_t* __restrict__ p1,
                                                const float* __restrict__ cs,
                                                const float* __restrict__ sn,
                                                ushort_t* __restrict__ qd,
                                                ushort_t* __restrict__ kd,
                                                ushort_t* __restrict__ vt) {
    __shared__ ushort_t tl[64][65];
    const int cx = blockIdx.x;               // 0..47
    const int ty = blockIdx.y;               // 0..31
    const int r  = threadIdx.x >> 2;         // 0..63
    const int c0 = (threadIdx.x & 3) << 4;   // 0,16,32,48
    const int t  = ty * 64 + r;
    const size_t base = (size_t)t * 3072 + cx * 64;

    if (cx < 40) {                           // q or k: combine + rope
        const int cp = c0 ^ 32;
        float own[16], par[16];
        #pragma unroll
        for (int jj = 0; jj < 2; jj++) {
            uint4 a = *(const uint4*)(p0 + base + c0 + jj * 8);
            uint4 b = *(const uint4*)(p1 + base + c0 + jj * 8);
            uint4 c = *(const uint4*)(p0 + base + cp + jj * 8);
            uint4 d = *(const uint4*)(p1 + base + cp + jj * 8);
            const ushort_t* pa = (const ushort_t*)&a;
            const ushort_t* pb = (const ushort_t*)&b;
            const ushort_t* pc = (const ushort_t*)&c;
            const ushort_t* pd = (const ushort_t*)&d;
            #pragma unroll
            for (int e = 0; e < 8; e++) {
                own[jj * 8 + e] = b2f(pa[e]) + b2f(pb[e]);
                par[jj * 8 + e] = b2f(pc[e]) + b2f(pd[e]);
            }
        }
        float cs16[16], sn16[16];
        #pragma unroll
        for (int jj = 0; jj < 4; jj++) {
            float4 c4 = *(const float4*)(cs + (size_t)t * 64 + c0 + jj * 4);
            float4 s4 = *(const float4*)(sn + (size_t)t * 64 + c0 + jj * 4);
            cs16[jj * 4 + 0] = c4.x; cs16[jj * 4 + 1] = c4.y;
            cs16[jj * 4 + 2] = c4.z; cs16[jj * 4 + 3] = c4.w;
            sn16[jj * 4 + 0] = s4.x; sn16[jj * 4 + 1] = s4.y;
            sn16[jj * 4 + 2] = s4.z; sn16[jj * 4 + 3] = s4.w;
        }
        const float scale = (cx < 32) ? 0.18033688f : 1.0f;  // q: (1/8)*log2e
        union { ushort_t u[16]; uint4 v[2]; } o;
        #pragma unroll
        for (int j = 0; j < 16; j++) {
            const int d = c0 + j;
            const float pr = (d < 32) ? -par[j] : par[j];
            o.u[j] = f2b((own[j] * cs16[j] + pr * sn16[j]) * scale);
        }
        if (cx < 32) {
            ushort_t* dst = qd + (size_t)t * 2048 + cx * 64 + c0;
            *(uint4*)dst = o.v[0]; *(uint4*)(dst + 8) = o.v[1];
        } else {
            ushort_t* dst = kd + (size_t)t * 512 + (cx - 32) * 64 + c0;
            *(uint4*)dst = o.v[0]; *(uint4*)(dst + 8) = o.v[1];
        }
    } else {                                 // v: combine + transpose via LDS
        #pragma unroll
        for (int jj = 0; jj < 2; jj++) {
            uint4 a = *(const uint4*)(p0 + base + c0 + jj * 8);
            uint4 b = *(const uint4*)(p1 + base + c0 + jj * 8);
            const ushort_t* pa = (const ushort_t*)&a;
            const ushort_t* pb = (const ushort_t*)&b;
            #pragma unroll
            for (int e = 0; e < 8; e++)
                tl[r][c0 + jj * 8 + e] = f2b(b2f(pa[e]) + b2f(pb[e]));
        }
        __syncthreads();
        const int rr  = threadIdx.x >> 3;        // 0..31
        const int cc8 = (threadIdx.x & 7) * 8;
        const int db = (cx - 40) * 64, tb = ty * 64;
        #pragma unroll
        for (int h = 0; h < 2; h++) {
            const int d = rr + h * 32;
            ushort4 o0, o1;
            o0.x = tl[cc8 + 0][d]; o0.y = tl[cc8 + 1][d];
            o0.z = tl[cc8 + 2][d]; o0.w = tl[cc8 + 3][d];
            o1.x = tl[cc8 + 4][d]; o1.y = tl[cc8 + 5][d];
            o1.z = tl[cc8 + 6][d]; o1.w = tl[cc8 + 7][d];
            *(ushort4*)(vt + (size_t)(db + d) * 2048 + tb + cc8)     = o0;
            *(ushort4*)(vt + (size_t)(db + d) * 2048 + tb + cc8 + 4) = o1;
        }
    }
}

// ---------- combine O partials -> fp32 out ----------
__global__ __launch_bounds__(256) void combine_o(const float4* __restrict__ s0,
                                                 const float4* __restrict__ s1,
                                                 float4* __restrict__ out) {
    for (int i = blockIdx.x * 256 + threadIdx.x; i < 1048576; i += 2048 * 256) {
        float4 a = s0[i], b = s1[i];
        float4 r; r.x = a.x + b.x; r.y = a.y + b.y; r.z = a.z + b.z; r.w = a.w + b.w;
        out[i] = r;
    }
}

// ---------- flash attention, causal, GQA G=4 (R6 verbatim) ----------
__global__ __launch_bounds__(256) void attn_kernel(const ushort_t* __restrict__ Q,
                                                   const ushort_t* __restrict__ Kb,
                                                   const ushort_t* __restrict__ Vt,
                                                   ushort_t* __restrict__ Ob) {
    __shared__ ushort_t Ks[2 * 4096];     // 16 KB: [buf][chunk d/8][s-row 64][8]
    __shared__ ushort_t Vs[2 * 4096];     // 16 KB: [buf][chunk s/8][d-row 64][8]
    __shared__ ushort_t pl[4 * 32 * 72];  // 18 KB: per-wave P, 32 rows x 64 (stride 72)
    const int tid  = threadIdx.x;
    const int lane = tid & 63, wid = tid >> 6;
    const int qn = lane & 15, quad = lane >> 4;
    const int h   = blockIdx.x & 31;
    const int qb  = 15 - (blockIdx.x >> 5);     // heavy first
    const int kvb = (h >> 2) * 64;
    const int trow = qb * 128 + wid * 32;
    ushort_t* plw = pl + wid * 32 * 72;
    f32x4 zero = {0.f, 0.f, 0.f, 0.f};

    const ushort_t* qpA = Q + (size_t)(trow + qn) * 2048 + h * 64 + quad * 8;
    const bf16x8 qA0 = ld8(qpA), qA1 = ld8(qpA + 32);
    const ushort_t* qpB = qpA + 16 * 2048;
    const bf16x8 qB0 = ld8(qpB), qB1 = ld8(qpB + 32);

    f32x4 oA[4] = {zero, zero, zero, zero};
    f32x4 oB[4] = {zero, zero, zero, zero};
    float lA[4] = {0.f, 0.f, 0.f, 0.f};
    float lB[4] = {0.f, 0.f, 0.f, 0.f};
    const int ntiles = qb * 2 + 2;

#define STAGE(s0, buf)                                                         \
    do {                                                                       \
        const ushort_t* kg = Kb + (size_t)((s0) + lane) * 512 + kvb + wid * 8; \
        gl_lds16(kg,      Ks + (buf) * 4096 + wid * 512);                      \
        gl_lds16(kg + 32, Ks + (buf) * 4096 + (wid + 4) * 512);                \
        const ushort_t* vg = Vt + (size_t)(kvb + lane) * 2048 + (s0) + wid * 8;\
        gl_lds16(vg,      Vs + (buf) * 4096 + wid * 512);                      \
        gl_lds16(vg + 32, Vs + (buf) * 4096 + (wid + 4) * 512);                \
    } while (0)

#define COMPUTE(s0, buf)                                                       \
    do {                                                                       \
        f32x4 scA[4], scB[4];                                                  \
        _Pragma("unroll")                                                      \
        for (int cb = 0; cb < 4; cb++) {                                       \
            const bf16x8 kf0 = *(const bf16x8*)(Ks + (buf) * 4096 + quad * 512 + (cb * 16 + qn) * 8);       \
            const bf16x8 kf1 = *(const bf16x8*)(Ks + (buf) * 4096 + (quad + 4) * 512 + (cb * 16 + qn) * 8); \
            f32x4 s = mfma16(qA0, kf0, zero); scA[cb] = mfma16(qA1, kf1, s);   \
            f32x4 t = mfma16(qB0, kf0, zero); scB[cb] = mfma16(qB1, kf1, t);   \
        }                                                                      \
        const bool needmask = ((s0) + 63 > trow);                              \
        _Pragma("unroll")                                                      \
        for (int i = 0; i < 4; i++) {                                          \
            const int tA = trow + quad * 4 + i, tB = tA + 16;                  \
            _Pragma("unroll")                                                  \
            for (int cb = 0; cb < 4; cb++) {                                   \
                const int col = (s0) + cb * 16 + qn;                           \
                float vA = scA[cb][i], vB = scB[cb][i];                        \
                if (needmask) {                                                \
                    if (col > tA) vA = -INFINITY;                              \
                    if (col > tB) vB = -INFINITY;                              \
                }                                                              \
                const float pA = fexp2(vA), pB = fexp2(vB);                    \
                lA[i] += pA; lB[i] += pB;                                      \
                plw[(quad * 4 + i) * 72 + cb * 16 + qn]      = f2b(pA);        \
                plw[(16 + quad * 4 + i) * 72 + cb * 16 + qn] = f2b(pB);        \
            }                                                                  \
        }                                                                      \
        const bf16x8 pfA0 = *(const bf16x8*)(plw + qn * 72 + quad * 8);        \
        const bf16x8 pfA1 = *(const bf16x8*)(plw + qn * 72 + 32 + quad * 8);   \
        const bf16x8 pfB0 = *(const bf16x8*)(plw + (16 + qn) * 72 + quad * 8); \
        const bf16x8 pfB1 = *(const bf16x8*)(plw + (16 + qn) * 72 + 32 + quad * 8); \
        _Pragma("unroll")                                                      \
        for (int dcb = 0; dcb < 4; dcb++) {                                    \
            const bf16x8 vf0 = *(const bf16x8*)(Vs + (buf) * 4096 + quad * 512 + (dcb * 16 + qn) * 8);       \
            const bf16x8 vf1 = *(const bf16x8*)(Vs + (buf) * 4096 + (quad + 4) * 512 + (dcb * 16 + qn) * 8); \
            oA[dcb] = mfma16(pfA0, vf0, oA[dcb]);                              \
            oA[dcb] = mfma16(pfA1, vf1, oA[dcb]);                              \
            oB[dcb] = mfma16(pfB0, vf0, oB[dcb]);                              \
            oB[dcb] = mfma16(pfB1, vf1, oB[dcb]);                              \
        }                                                                      \
    } while (0)

    STAGE(0, 0);
    for (int t = 0; t < ntiles; t += 2) {
        __syncthreads();
        STAGE((t + 1) * 64, 1);
        COMPUTE(t * 64, 0);
        __syncthreads();
        if (t + 2 < ntiles) STAGE((t + 2) * 64, 0);
        COMPUTE((t + 1) * 64, 1);
    }
#undef STAGE
#undef COMPUTE

    #pragma unroll
    for (int i = 0; i < 4; i++) {
        float sA = lA[i], sB = lB[i];
        #pragma unroll
        for (int off = 1; off < 16; off <<= 1) {
            sA += __shfl_xor(sA, off, 64);
            sB += __shfl_xor(sB, off, 64);
        }
        const float invA = 1.0f / sA, invB = 1.0f / sB;
        ushort_t* obA = Ob + (size_t)(trow + quad * 4 + i) * 2048 + h * 64 + qn;
        ushort_t* obB = obA + 16 * 2048;
        obA[0]  = f2b(oA[0][i] * invA);
        obA[16] = f2b(oA[1][i] * invA);
        obA[32] = f2b(oA[2][i] * invA);
        obA[48] = f2b(oA[3][i] * invA);
        obB[0]  = f2b(oB[0][i] * invB);
        obB[16] = f2b(oB[1][i] * invB);
        obB[32] = f2b(oB[2][i] * invB);
        obB[48] = f2b(oB[3][i] * invB);
    }
}

// ---------- launch ----------
extern "C" void kernel_launch(void* const* d_in, const int* in_sizes, int n_in,
                              void* d_out, int out_size, void* d_ws, size_t ws_size,
                              hipStream_t stream) {
    const float* x    = (const float*)d_in[0];
    const float* cosp = (const float*)d_in[1];
    const float* sinp = (const float*)d_in[2];
    // d_in[3] = attention_mask_4d (pure causal; recomputed in-kernel)
    const float* Wq = (const float*)d_in[4];
    const float* Wk = (const float*)d_in[5];
    const float* Wv = (const float*)d_in[6];
    const float* Wo = (const float*)d_in[7];
    char* ws = (char*)d_ws;
    (void)ws_size; (void)in_sizes; (void)n_in; (void)out_size;

    ushort_t* xb    = (ushort_t*)(ws + WS_XB);
    ushort_t* wqkvb = (ushort_t*)(ws + WS_WQKV);
    ushort_t* wob   = (ushort_t*)(ws + WS_WO);
    ushort_t* p0    = (ushort_t*)(ws + WS_P0);
    ushort_t* p1    = (ushort_t*)(ws + WS_P1);
    ushort_t* qbb   = (ushort_t*)(ws + WS_QBB);
    ushort_t* kbb   = (ushort_t*)(ws + WS_KBB);
    ushort_t* vtg   = (ushort_t*)(ws + WS_VTG);
    ushort_t* ab    = (ushort_t*)(ws + WS_AB);
    float*    o0    = (float*)   (ws + WS_O0);
    float*    o1    = (float*)   (ws + WS_O1);

    // 1. convert inputs/weights to bf16 (contiguous dst: xb|wqkvb|wob)
    cvt_all<<<14336, 256, 0, stream>>>(x, Wq, Wk, Wv, Wo, xb);

    // 2. QKV projection split-K=2: 768 blocks (3/CU), bf16 partial slabs
    gemm_split<1><<<dim3(24, 16, 2), 256, 0, stream>>>(xb, wqkvb, p0, p1, 3072, 2048);

    // 3. fused combine + RoPE(q scale=(1/8)*log2e) + V transpose
    fuse_crv<<<dim3(48, 32), 256, 0, stream>>>(p0, p1, cosp, sinp, qbb, kbb, vtg);

    // 4. attention (proven R6 kernel)
    attn_kernel<<<512, 256, 0, stream>>>(qbb, kbb, vtg, ab);

    // 5. O-projection split-K=2: 512 blocks (2/CU), fp32 partial slabs
    gemm_split<0><<<dim3(16, 16, 2), 256, 0, stream>>>(ab, wob, o0, o1, 2048, 2048);

    // 6. combine partials into fp32 output
    combine_o<<<2048, 256, 0, stream>>>((const float4*)o0, (const float4*)o1,
                                        (float4*)d_out);
}